// Round 4
// baseline (1053.912 us; speedup 1.0000x reference)
//
#include <hip/hip_runtime.h>
#include <hip/hip_bf16.h>
#include <cstdint>
#include <math.h>

// Problem constants
#define NB 512
#define NS 128
#define ND 512
#define NH 8
#define NDK 64
#define NFF 2048

typedef __attribute__((ext_vector_type(4))) float f32x4;
typedef __attribute__((ext_vector_type(8))) short s16x8;

#define AS1 __attribute__((address_space(1)))
#define AS3 __attribute__((address_space(3)))

__device__ __forceinline__ ushort f2b(float f) {
  __hip_bfloat16 h = __float2bfloat16(f);
  return *reinterpret_cast<ushort*>(&h);
}
__device__ __forceinline__ float b2f(ushort u) {
  __hip_bfloat16 h;
  *reinterpret_cast<ushort*>(&h) = u;
  return __bfloat162float(h);
}
// global -> LDS direct copy, 16B per lane. LDS dest is wave-uniform base;
// HW writes base + lane*16 (guide m97/m104). Global src is per-lane.
__device__ __forceinline__ void gll16(const void* g, void* l) {
  __builtin_amdgcn_global_load_lds(
      (const AS1 unsigned int*)g,
      reinterpret_cast<AS3 unsigned int*>(reinterpret_cast<uintptr_t>(l)),
      16, 0, 0);
}

// ---------------------------------------------------------------- pack kernels
__global__ void conv_bf16(const float* __restrict__ in, ushort* __restrict__ out, int n4) {
  int i = blockIdx.x * blockDim.x + threadIdx.x;
  if (i >= n4) return;
  float4 v = *(const float4*)(in + (size_t)i * 4);
  ushort4 o;
  o.x = f2b(v.x); o.y = f2b(v.y); o.z = f2b(v.z); o.w = f2b(v.w);
  *(ushort4*)(out + (size_t)i * 4) = o;
}

// transpose-convert: in [R][C] fp32 -> out [C][R] bf16
__global__ void pack_t(const float* __restrict__ in, ushort* __restrict__ out, int R, int C) {
  int i = blockIdx.x * blockDim.x + threadIdx.x;
  if (i >= R * C) return;
  int r = i / C, c = i - r * C;
  out[(size_t)c * R + r] = f2b(in[i]);
}

// wqkvT[h][n][d]: n<64 -> WQ[h][d][n]*0.125 ; n<128 -> WK ; else WV
__global__ void pack_qkv(const float* __restrict__ WQ, const float* __restrict__ WK,
                         const float* __restrict__ WV, ushort* __restrict__ out) {
  int i = blockIdx.x * blockDim.x + threadIdx.x;
  if (i >= NH * 192 * ND) return;
  int h = i / (192 * ND);
  int rem = i - h * (192 * ND);
  int n = rem / ND, d = rem - n * ND;
  size_t base = (size_t)h * ND * NDK + (size_t)d * NDK;
  float v;
  if (n < 64)       v = WQ[base + n] * 0.125f;
  else if (n < 128) v = WK[base + (n - 64)];
  else              v = WV[base + (n - 128)];
  out[i] = f2b(v);
}

__global__ void pe_build(float* __restrict__ pe) {
  int i = blockIdx.x * blockDim.x + threadIdx.x;
  if (i >= NS * ND) return;
  int s = i >> 9, d = i & 511;
  float e = expf((float)(d & ~1) * (-9.210340371976184f / 512.f)); // ln(10000)
  float ang = (float)s * e;
  pe[i] = (d & 1) ? cosf(ang) : sinf(ang);
}

// ---------------------------------------------------------------- generic GEMM
// C[M,N] = A[M,K](bf16) @ Bt[N,K]^T(bf16), 128x128 tile, BK=32, dbuf m97-style.
// EPI 0: +bias +PE -> bf16 Obf (embed->h)
// EPI 1: +res(bf16 h) -> fp32 Of (r) + LN stats atomics
// EPI 2: +bias, relu -> bf16 Obf (ffn1)
// EPI 3: +bias, fused 16x16 maxpool -> pool[b][256]
template <int EPI>
__global__ __launch_bounds__(256, 2) void gemm_bf16(
    const ushort* __restrict__ A, const ushort* __restrict__ Bt,
    int M, int N, int K,
    ushort* __restrict__ Obf, float* __restrict__ Of,
    const float* __restrict__ bias, const float* __restrict__ pe,
    const ushort* __restrict__ res, float* __restrict__ stats,
    float* __restrict__ pool) {
  __shared__ __align__(16) ushort lA[2][4096];  // [128][32]
  __shared__ __align__(16) ushort lB[2][4096];  // [128][32]
  const int tid = threadIdx.x, lane = tid & 63, wid = tid >> 6;
  const int wr = wid >> 1, wc = wid & 1;
  const int lo = lane & 15, hi = lane >> 4;
  const int ntil = N >> 7;
  const int bm = blockIdx.x / ntil, bn = blockIdx.x - bm * ntil;
  const int m0 = bm << 7, n0 = bn << 7;
  const int rr = lane >> 2, cc = (lane & 3) << 3;

  f32x4 acc[4][4];
#pragma unroll
  for (int m = 0; m < 4; ++m)
#pragma unroll
    for (int n = 0; n < 4; ++n) acc[m][n] = (f32x4){0.f, 0.f, 0.f, 0.f};

  const int nk = K >> 5;
  for (int s = wid; s < 8; s += 4) {
    gll16(&A[(size_t)(m0 + s * 16 + rr) * K + cc], &lA[0][s * 512]);
    gll16(&Bt[(size_t)(n0 + s * 16 + rr) * K + cc], &lB[0][s * 512]);
  }
  __syncthreads();
  for (int t = 0; t < nk; ++t) {
    const int cur = t & 1;
    if (t + 1 < nk) {
      const int k0 = (t + 1) << 5;
      for (int s = wid; s < 8; s += 4) {
        gll16(&A[(size_t)(m0 + s * 16 + rr) * K + k0 + cc], &lA[cur ^ 1][s * 512]);
        gll16(&Bt[(size_t)(n0 + s * 16 + rr) * K + k0 + cc], &lB[cur ^ 1][s * 512]);
      }
    }
    s16x8 af[4], bfr[4];
#pragma unroll
    for (int m = 0; m < 4; ++m)
      af[m] = *(const s16x8*)&lA[cur][(wr * 64 + m * 16 + lo) * 32 + hi * 8];
#pragma unroll
    for (int n = 0; n < 4; ++n)
      bfr[n] = *(const s16x8*)&lB[cur][(wc * 64 + n * 16 + lo) * 32 + hi * 8];
#pragma unroll
    for (int m = 0; m < 4; ++m)
#pragma unroll
      for (int n = 0; n < 4; ++n)
        acc[m][n] = __builtin_amdgcn_mfma_f32_16x16x32_bf16(af[m], bfr[n], acc[m][n], 0, 0, 0);
    __syncthreads();
  }

  if constexpr (EPI == 0) {
#pragma unroll
    for (int m = 0; m < 4; ++m)
#pragma unroll
      for (int n = 0; n < 4; ++n) {
        const int col = n0 + wc * 64 + n * 16 + lo;
        const float bv = bias[col];
#pragma unroll
        for (int j = 0; j < 4; ++j) {
          const int row = m0 + wr * 64 + m * 16 + hi * 4 + j;
          const float v = acc[m][n][j] + bv + pe[((row & 127) << 9) + col];
          Obf[(size_t)row * N + col] = f2b(v);
        }
      }
  } else if constexpr (EPI == 1) {
    float s1 = 0.f, s2 = 0.f;
#pragma unroll
    for (int m = 0; m < 4; ++m)
#pragma unroll
      for (int n = 0; n < 4; ++n) {
        const int col = n0 + wc * 64 + n * 16 + lo;
#pragma unroll
        for (int j = 0; j < 4; ++j) {
          const int row = m0 + wr * 64 + m * 16 + hi * 4 + j;
          const float v = acc[m][n][j] + b2f(res[(size_t)row * 512 + col]);
          Of[(size_t)row * 512 + col] = v;
          s1 += v; s2 += v * v;
        }
      }
    s1 += __shfl_xor(s1, 1);  s2 += __shfl_xor(s2, 1);
    s1 += __shfl_xor(s1, 2);  s2 += __shfl_xor(s2, 2);
    s1 += __shfl_xor(s1, 4);  s2 += __shfl_xor(s2, 4);
    s1 += __shfl_xor(s1, 8);  s2 += __shfl_xor(s2, 8);
    s1 += __shfl_xor(s1, 16); s2 += __shfl_xor(s2, 16);
    s1 += __shfl_xor(s1, 32); s2 += __shfl_xor(s2, 32);
    if (lane == 0) {
      atomicAdd(&stats[bm * 2], s1);
      atomicAdd(&stats[bm * 2 + 1], s2);
    }
  } else if constexpr (EPI == 2) {
#pragma unroll
    for (int m = 0; m < 4; ++m)
#pragma unroll
      for (int n = 0; n < 4; ++n) {
        const int col = n0 + wc * 64 + n * 16 + lo;
        const float bv = bias[col];
#pragma unroll
        for (int j = 0; j < 4; ++j) {
          const int row = m0 + wr * 64 + m * 16 + hi * 4 + j;
          Obf[(size_t)row * N + col] = f2b(fmaxf(acc[m][n][j] + bv, 0.f));
        }
      }
  } else {  // EPI 3: fused maxpool 16x16 -> pool[b*256 + sg*32 + dg]
#pragma unroll
    for (int m = 0; m < 4; ++m)
#pragma unroll
      for (int n = 0; n < 4; ++n) {
        const int col = n0 + wc * 64 + n * 16 + lo;
        float fv = fmaxf(fmaxf(acc[m][n][0], acc[m][n][1]),
                         fmaxf(acc[m][n][2], acc[m][n][3])) + bias[col];
        fv = fmaxf(fv, __shfl_xor(fv, 1));
        fv = fmaxf(fv, __shfl_xor(fv, 2));
        fv = fmaxf(fv, __shfl_xor(fv, 4));
        fv = fmaxf(fv, __shfl_xor(fv, 8));
        fv = fmaxf(fv, __shfl_xor(fv, 16));
        fv = fmaxf(fv, __shfl_xor(fv, 32));
        if (lane == 0)
          pool[bm * 256 + (wr * 4 + m) * 32 + (bn * 8 + wc * 4 + n)] = fv;
      }
  }
}

// ---------------------------------------------------------------- attention
// one block per (b, head): QKV proj -> scores -> softmax -> PV -> o
__global__ __launch_bounds__(256, 2) void attn_fused(
    const ushort* __restrict__ h, const ushort* __restrict__ wqkvT,
    ushort* __restrict__ o) {
  // 64KB LDS, region-reused:
  // smem[0..16384)   ushort: staging (A 4096 + B 6144) -> q[128][64] -> P lower half
  // smem[16384..24576) kbuf [128][64]   (aliased by redm/reds after scores)
  // smem[24576..32768) vT  [64][128]
  // P occupies smem[0..16384) as [128][128]
  __shared__ __align__(16) ushort smem[32768];
  ushort* uni = smem;
  ushort* kb = smem + 16384;
  ushort* vT = smem + 24576;
  float* redm = (float*)(smem + 16384);  // 256 floats, alias kb (safe post-scores)
  float* reds = redm + 256;

  const int tid = threadIdx.x, lane = tid & 63, wid = tid >> 6;
  const int wr = wid >> 1, wc = wid & 1;
  const int lo = lane & 15, hi = lane >> 4;
  const int bh = blockIdx.x;
  const int b = bh >> 3, hd = bh & 7;
  const ushort* hsrc = h + (size_t)b * (NS * ND);
  const ushort* wsrc = wqkvT + (size_t)hd * (192 * ND);
  const int rr = lane >> 2, cc = (lane & 3) << 3;

  // ---- QKV: [128,512] @ [512,192]^T(Bt form), wave tile 64x96
  f32x4 a1[4][6];
#pragma unroll
  for (int m = 0; m < 4; ++m)
#pragma unroll
    for (int n = 0; n < 6; ++n) a1[m][n] = (f32x4){0.f, 0.f, 0.f, 0.f};
  for (int t = 0; t < 16; ++t) {
    const int k0 = t << 5;
    for (int s = wid; s < 8; s += 4)
      gll16(&hsrc[(size_t)(s * 16 + rr) * ND + k0 + cc], &uni[s * 512]);
    for (int s = wid; s < 12; s += 4)
      gll16(&wsrc[(size_t)(s * 16 + rr) * ND + k0 + cc], &uni[4096 + s * 512]);
    __syncthreads();
    s16x8 af[4], bfr[6];
#pragma unroll
    for (int m = 0; m < 4; ++m)
      af[m] = *(const s16x8*)&uni[(wr * 64 + m * 16 + lo) * 32 + hi * 8];
#pragma unroll
    for (int n = 0; n < 6; ++n)
      bfr[n] = *(const s16x8*)&uni[4096 + (wc * 96 + n * 16 + lo) * 32 + hi * 8];
#pragma unroll
    for (int m = 0; m < 4; ++m)
#pragma unroll
      for (int n = 0; n < 6; ++n)
        a1[m][n] = __builtin_amdgcn_mfma_f32_16x16x32_bf16(af[m], bfr[n], a1[m][n], 0, 0, 0);
    __syncthreads();
  }
  // scatter to q (uni[0..8192)), kb, vT(transposed)
#pragma unroll
  for (int m = 0; m < 4; ++m)
#pragma unroll
    for (int n = 0; n < 6; ++n)
#pragma unroll
      for (int j = 0; j < 4; ++j) {
        const int row = wr * 64 + m * 16 + hi * 4 + j;
        const int c = wc * 96 + n * 16 + lo;
        const ushort v = f2b(a1[m][n][j]);
        if (c < 64) uni[row * 64 + c] = v;
        else if (c < 128) kb[row * 64 + (c - 64)] = v;
        else vT[(c - 128) * 128 + row] = v;
      }
  __syncthreads();

  // ---- scores: q[128,64] @ k^T -> [128,128], wave tile 64x64
  f32x4 sc[4][4];
#pragma unroll
  for (int m = 0; m < 4; ++m)
#pragma unroll
    for (int n = 0; n < 4; ++n) sc[m][n] = (f32x4){0.f, 0.f, 0.f, 0.f};
#pragma unroll
  for (int kt = 0; kt < 2; ++kt) {
    s16x8 aq[4], bk[4];
#pragma unroll
    for (int m = 0; m < 4; ++m)
      aq[m] = *(const s16x8*)&uni[(wr * 64 + m * 16 + lo) * 64 + kt * 32 + hi * 8];
#pragma unroll
    for (int n = 0; n < 4; ++n)
      bk[n] = *(const s16x8*)&kb[(wc * 64 + n * 16 + lo) * 64 + kt * 32 + hi * 8];
#pragma unroll
    for (int m = 0; m < 4; ++m)
#pragma unroll
      for (int n = 0; n < 4; ++n)
        sc[m][n] = __builtin_amdgcn_mfma_f32_16x16x32_bf16(aq[m], bk[n], sc[m][n], 0, 0, 0);
  }
  __syncthreads();  // all q/k reads done: kb region may be reused as red bufs

  // ---- softmax (rows), cross-wave via redm/reds
  float rmax[4][4];
#pragma unroll
  for (int m = 0; m < 4; ++m)
#pragma unroll
    for (int j = 0; j < 4; ++j) {
      float v = fmaxf(fmaxf(sc[m][0][j], sc[m][1][j]), fmaxf(sc[m][2][j], sc[m][3][j]));
      v = fmaxf(v, __shfl_xor(v, 1));
      v = fmaxf(v, __shfl_xor(v, 2));
      v = fmaxf(v, __shfl_xor(v, 4));
      v = fmaxf(v, __shfl_xor(v, 8));
      rmax[m][j] = v;
    }
  if (lo == 0) {
#pragma unroll
    for (int m = 0; m < 4; ++m)
#pragma unroll
      for (int j = 0; j < 4; ++j)
        redm[wc * 128 + wr * 64 + m * 16 + hi * 4 + j] = rmax[m][j];
  }
  __syncthreads();
  float rsum[4][4];
#pragma unroll
  for (int m = 0; m < 4; ++m)
#pragma unroll
    for (int j = 0; j < 4; ++j) {
      const int row = wr * 64 + m * 16 + hi * 4 + j;
      const float mx = fmaxf(redm[row], redm[128 + row]);
      float s = 0.f;
#pragma unroll
      for (int n = 0; n < 4; ++n) {
        const float p = __expf(sc[m][n][j] - mx);
        uni[row * 128 + wc * 64 + n * 16 + lo] = f2b(p);  // P overlays q (dead)
        s += p;
      }
      s += __shfl_xor(s, 1);
      s += __shfl_xor(s, 2);
      s += __shfl_xor(s, 4);
      s += __shfl_xor(s, 8);
      rsum[m][j] = s;
    }
  if (lo == 0) {
#pragma unroll
    for (int m = 0; m < 4; ++m)
#pragma unroll
      for (int j = 0; j < 4; ++j)
        reds[wc * 128 + wr * 64 + m * 16 + hi * 4 + j] = rsum[m][j];
  }
  __syncthreads();
  float inv[4][4];
#pragma unroll
  for (int m = 0; m < 4; ++m)
#pragma unroll
    for (int j = 0; j < 4; ++j) {
      const int row = wr * 64 + m * 16 + hi * 4 + j;
      inv[m][j] = 1.f / (reds[row] + reds[128 + row]);
    }

  // ---- PV: P[128,128] @ v[128,64], wave tile 64x32
  f32x4 oa[4][2];
#pragma unroll
  for (int m = 0; m < 4; ++m)
#pragma unroll
    for (int n = 0; n < 2; ++n) oa[m][n] = (f32x4){0.f, 0.f, 0.f, 0.f};
#pragma unroll
  for (int kt = 0; kt < 4; ++kt) {
    s16x8 ap[4], bv[2];
#pragma unroll
    for (int m = 0; m < 4; ++m)
      ap[m] = *(const s16x8*)&uni[(wr * 64 + m * 16 + lo) * 128 + kt * 32 + hi * 8];
#pragma unroll
    for (int n = 0; n < 2; ++n)
      bv[n] = *(const s16x8*)&vT[(wc * 32 + n * 16 + lo) * 128 + kt * 32 + hi * 8];
#pragma unroll
    for (int m = 0; m < 4; ++m)
#pragma unroll
      for (int n = 0; n < 2; ++n)
        oa[m][n] = __builtin_amdgcn_mfma_f32_16x16x32_bf16(ap[m], bv[n], oa[m][n], 0, 0, 0);
  }
#pragma unroll
  for (int m = 0; m < 4; ++m)
#pragma unroll
    for (int n = 0; n < 2; ++n)
#pragma unroll
      for (int j = 0; j < 4; ++j) {
        const int row = wr * 64 + m * 16 + hi * 4 + j;
        const int c = wc * 32 + n * 16 + lo;
        o[((size_t)b * NS + row) * ND + hd * 64 + c] = f2b(oa[m][n][j] * inv[m][j]);
      }
}

// ---------------------------------------------------------------- LN apply
__global__ void ln_apply(const float* __restrict__ r, const float* __restrict__ stats,
                         const float* __restrict__ nw, const float* __restrict__ nb,
                         ushort* __restrict__ rn) {
  int i = blockIdx.x * blockDim.x + threadIdx.x;  // x4 elements
  int base = i << 2;
  if (base >= NB * NS * ND) return;
  int b = base >> 16;     // / (S*D=65536)
  int sd = base & 65535;
  float mu = stats[2 * b] * (1.f / 65536.f);
  float var = stats[2 * b + 1] * (1.f / 65536.f) - mu * mu;
  float rs = rsqrtf(var + 1e-5f);
  float4 rv = *(const float4*)(r + base);
  float4 w = *(const float4*)(nw + sd);
  float4 bb = *(const float4*)(nb + sd);
  ushort4 ov;
  ov.x = f2b((rv.x - mu) * rs * w.x + bb.x);
  ov.y = f2b((rv.y - mu) * rs * w.y + bb.y);
  ov.z = f2b((rv.z - mu) * rs * w.z + bb.z);
  ov.w = f2b((rv.w - mu) * rs * w.w + bb.w);
  *(ushort4*)(rn + base) = ov;
}

// ---------------------------------------------------------------- final fc
__global__ void fc_logsoftmax(const float* __restrict__ p, const float* __restrict__ w,
                              const float* __restrict__ bias, float* __restrict__ out) {
  int b = blockIdx.x * blockDim.x + threadIdx.x;
  if (b >= NB) return;
  float l0 = bias[0], l1 = bias[1];
  const float* pr = p + b * 256;
  for (int k = 0; k < 256; ++k) {
    float pv = pr[k];
    l0 += pv * w[2 * k];
    l1 += pv * w[2 * k + 1];
  }
  float mx = fmaxf(l0, l1);
  float lse = mx + logf(expf(l0 - mx) + expf(l1 - mx));
  out[2 * b] = l0 - lse;
  out[2 * b + 1] = l1 - lse;
}

// ---------------------------------------------------------------- launch
extern "C" void kernel_launch(void* const* d_in, const int* in_sizes, int n_in,
                              void* d_out, int out_size, void* d_ws, size_t ws_size,
                              hipStream_t stream) {
  const float* x      = (const float*)d_in[0];
  const float* emb_w  = (const float*)d_in[1];
  const float* emb_b  = (const float*)d_in[2];
  const float* WQ     = (const float*)d_in[3];
  const float* WK     = (const float*)d_in[4];
  const float* WV     = (const float*)d_in[5];
  const float* WO     = (const float*)d_in[6];
  const float* norm_w = (const float*)d_in[7];
  const float* norm_b = (const float*)d_in[8];
  const float* l1_w   = (const float*)d_in[9];
  const float* l1_b   = (const float*)d_in[10];
  const float* l2_w   = (const float*)d_in[11];
  const float* l2_b   = (const float*)d_in[12];
  const float* fc_w   = (const float*)d_in[13];
  const float* fc_b   = (const float*)d_in[14];
  float* out = (float*)d_out;
  char* ws = (char*)d_ws;

  constexpr size_t MB = 1ull << 20;
  // region A (overlaid by f1 later): xb, h, o, r(fp32)
  ushort* xb   = (ushort*)(ws + 0);          // 64 MB bf16 [B*S, D]
  ushort* hbuf = (ushort*)(ws + 64 * MB);    // 64 MB
  ushort* obuf = (ushort*)(ws + 128 * MB);   // 64 MB
  float*  rbuf = (float*)(ws + 192 * MB);    // 128 MB fp32
  ushort* f1   = (ushort*)(ws + 0);          // 256 MB overlay (xb,h,o,r dead)
  ushort* rnb  = (ushort*)(ws + 320 * MB);   // 64 MB
  char* wb = ws + 384 * MB;
  ushort* embT  = (ushort*)(wb);                  // 512 KB
  ushort* woT   = (ushort*)(wb + 524288);         // 512 KB
  ushort* l1T   = (ushort*)(wb + 1048576);        // 2 MB
  ushort* l2T   = (ushort*)(wb + 3145728);        // 2 MB
  ushort* wqkvT = (ushort*)(wb + 5242880);        // 1.5 MB
  float*  peb   = (float*)(wb + 6815744);         // 256 KB
  float*  stats = (float*)(wb + 7077888);         // 4 KB
  float*  poolb = (float*)(wb + 7086080);         // 512 KB

  hipMemsetAsync(stats, 0, NB * 2 * sizeof(float), stream);

  conv_bf16<<<32768, 256, 0, stream>>>(x, xb, NB * NS * ND / 4);
  pe_build<<<256, 256, 0, stream>>>(peb);
  pack_t<<<1024, 256, 0, stream>>>(emb_w, embT, 512, 512);
  pack_t<<<1024, 256, 0, stream>>>(WO, woT, 512, 512);
  pack_t<<<4096, 256, 0, stream>>>(l1_w, l1T, 512, 2048);
  pack_t<<<4096, 256, 0, stream>>>(l2_w, l2T, 2048, 512);
  pack_qkv<<<3072, 256, 0, stream>>>(WQ, WK, WV, wqkvT);

  // h = x@emb_w + emb_b + PE
  gemm_bf16<0><<<2048, 256, 0, stream>>>(xb, embT, NB * NS, ND, ND,
                                         hbuf, nullptr, emb_b, peb, nullptr, nullptr, nullptr);
  // attention -> o
  attn_fused<<<NB * NH, 256, 0, stream>>>(hbuf, wqkvT, obuf);
  // r = o@WO + h (fp32) + LN stats
  gemm_bf16<1><<<2048, 256, 0, stream>>>(obuf, woT, NB * NS, ND, ND,
                                         nullptr, rbuf, nullptr, nullptr, hbuf, stats, nullptr);
  // rn = LN(r)
  ln_apply<<<32768, 256, 0, stream>>>(rbuf, stats, norm_w, norm_b, rnb);
  // f1 = relu(rn@l1 + b1)
  gemm_bf16<2><<<8192, 256, 0, stream>>>(rnb, l1T, NB * NS, NFF, ND,
                                         f1, nullptr, l1_b, nullptr, nullptr, nullptr, nullptr);
  // pool = maxpool16x16(f1@l2 + b2)
  gemm_bf16<3><<<2048, 256, 0, stream>>>(f1, l2T, NB * NS, ND, NFF,
                                         nullptr, nullptr, l2_b, nullptr, nullptr, nullptr, poolb);
  // logits + log_softmax
  fc_logsoftmax<<<2, 256, 0, stream>>>(poolb, fc_w, fc_b, out);
}